// Round 16
// baseline (202.123 us; speedup 1.0000x reference)
//
#include <hip/hip_runtime.h>
#include <hip/hip_bf16.h>

// B=4, N=2048, D=1024, H=16, hd=64. Full bf16-MFMA pipeline:
//  convert x / transpose-convert weights -> bf16
//  qkv GEMM (r8 128x128 2-phase dbuf + L2-GROUPED XCD grid)   [r15, best]
//  flash attention MFMA (swapped QK^T, static-max softmax, blocked-LDS,
//                        T14 ASYNC REG-STAGING: load->regs before compute,
//                        ds_write after barrier; no extra LDS)
//  proj GEMM (r8 128x128 2-phase dbuf, swapped-operand float4 epilogue)

typedef short bf16x8 __attribute__((ext_vector_type(8)));
typedef float f32x4 __attribute__((ext_vector_type(4)));
typedef unsigned short u16;
typedef u16 u16x8 __attribute__((ext_vector_type(8)));
typedef u16 u16x4 __attribute__((ext_vector_type(4)));

__device__ __forceinline__ u16 f2b(float f) {
    unsigned u = __builtin_bit_cast(unsigned, f);
    unsigned r = (u + 0x7fffu + ((u >> 16) & 1u)) >> 16;
    return (u16)r;
}

// v_cvt_pk_bf16_f32: a -> low16 (RNE), b -> high16
__device__ __forceinline__ unsigned cvt_pk(float a, float b) {
    unsigned r;
    asm("v_cvt_pk_bf16_f32 %0, %1, %2" : "=v"(r) : "v"(a), "v"(b));
    return r;
}

__device__ __forceinline__ float exp2_(float x) {
#if __has_builtin(__builtin_amdgcn_exp2f)
    return __builtin_amdgcn_exp2f(x);
#else
    return __expf(x * 0.69314718055994531f);
#endif
}

__device__ __forceinline__ void gload16(const void* g, void* lds) {
    __builtin_amdgcn_global_load_lds(
        (const __attribute__((address_space(1))) unsigned int*)g,
        (__attribute__((address_space(3))) unsigned int*)lds, 16, 0, 0);
}

#define MFMA16(a, b, c) __builtin_amdgcn_mfma_f32_16x16x32_bf16(a, b, c, 0, 0, 0)

// ---------------------------------------------------------------------------
__global__ __launch_bounds__(256) void convert_x_kernel(
    const float* __restrict__ in, u16* __restrict__ out)
{
    int i = blockIdx.x * 256 + threadIdx.x;
    const float4* ip = (const float4*)in;
    float4 a = ip[2 * i], b = ip[2 * i + 1];
    u16x8 r;
    r[0] = f2b(a.x); r[1] = f2b(a.y); r[2] = f2b(a.z); r[3] = f2b(a.w);
    r[4] = f2b(b.x); r[5] = f2b(b.y); r[6] = f2b(b.z); r[7] = f2b(b.w);
    *(u16x8*)&out[(size_t)i * 8] = r;
}

// in [R][C] fp32 -> out [C][R] bf16
__global__ __launch_bounds__(256) void transpose_conv_kernel(
    const float* __restrict__ in, u16* __restrict__ out, int R, int C)
{
    __shared__ float T[32][33];
    const int bj = blockIdx.x, bi = blockIdx.y;
    const int tx = threadIdx.x, ty = threadIdx.y;     // 32 x 8
#pragma unroll
    for (int k = 0; k < 4; ++k)
        T[ty + k * 8][tx] = in[(size_t)(bi * 32 + ty + k * 8) * C + bj * 32 + tx];
    __syncthreads();
#pragma unroll
    for (int k = 0; k < 4; ++k)
        out[(size_t)(bj * 32 + ty + k * 8) * R + bi * 32 + tx] = f2b(T[tx][ty + k * 8]);
}

// ---------------------------------------------------------------------------
// 128x128 tile bf16 GEMM, BK=32, 4 waves, 4x4 16x16 frags/wave (r8 structure).
// 2-phase dbuf: STAGE(next) before COMPUTE(cur), one __syncthreads per step.
// L2-GROUPED XCD grid: XCD x owns bm in [x*8, x*8+8); within an XCD, blocks
// ordered in 8bm x 8bn groups (A-strip 2MB + B-panel 2MB stay L2-hot).
// Q/K blocks: swapped operands -> u16x4 stores; V: normal -> u16x4 to Vt.
// ---------------------------------------------------------------------------
__global__ __launch_bounds__(256) void gemm_qkv_mfma(
    const u16* __restrict__ A,    // xb [8192][1024]
    const u16* __restrict__ Bt,   // wqT [3072][1024]
    u16* __restrict__ Q, u16* __restrict__ K, u16* __restrict__ Vt)
{
    __shared__ u16 As[2][128 * 32];
    __shared__ u16 Bs[2][128 * 32];
    const int tid = threadIdx.x;
    const int w = tid >> 6, lane = tid & 63;
    // L2-grouped XCD swizzle: 1536 = 8 XCD x 3 groups x (8bm x 8bn)
    const int flat = blockIdx.y * 24 + blockIdx.x;
    const int xcd = flat & 7, idx = flat >> 3;        // idx 0..191
    const int g = idx >> 6, rem = idx & 63;           // g 0..2
    const int bm = xcd * 8 + (rem >> 3);              // 0..63
    const int bn = g * 8 + (rem & 7);                 // 0..23
    const int wm = (w >> 1) * 64, wn = (w & 1) * 64;
    const int lo = lane & 15, hi = lane >> 4;
    const int arow0 = w * 16 + (lane >> 2);
    const int akc = (lane & 3) * 8;
    const int which = g;                  // 0=Q 1=K 2=V (block-uniform)

    f32x4 acc[4][4] = {};

    auto STAGE = [&](int bsel, int kt) {
#pragma unroll
        for (int j = 0; j < 2; ++j) {
            int row = j * 64 + arow0;
            gload16(&A[(size_t)(bm * 128 + row) * 1024 + kt + akc], &As[bsel][(j * 4 + w) * 512]);
            gload16(&Bt[(size_t)(bn * 128 + row) * 1024 + kt + akc], &Bs[bsel][(j * 4 + w) * 512]);
        }
    };

    auto COMPUTE = [&](int bsel) {
        bf16x8 a[4], b[4];
#pragma unroll
        for (int f = 0; f < 4; ++f) {
            a[f] = *(const bf16x8*)&As[bsel][(wm + f * 16 + lo) * 32 + hi * 8];
            b[f] = *(const bf16x8*)&Bs[bsel][(wn + f * 16 + lo) * 32 + hi * 8];
        }
        if (which == 2) {
#pragma unroll
            for (int fi = 0; fi < 4; ++fi)
#pragma unroll
                for (int fj = 0; fj < 4; ++fj)
                    acc[fi][fj] = MFMA16(a[fi], b[fj], acc[fi][fj]);   // C[m][c]
        } else {
#pragma unroll
            for (int fi = 0; fi < 4; ++fi)
#pragma unroll
                for (int fj = 0; fj < 4; ++fj)
                    acc[fi][fj] = MFMA16(b[fj], a[fi], acc[fi][fj]);   // C^T: [c][m]
        }
    };

    STAGE(0, 0);
    __syncthreads();                       // buf0 staged (implicit vmcnt(0))
    for (int t = 0; t < 32; t += 2) {
        STAGE(1, (t + 1) * 32);            // prefetch overlaps compute
        COMPUTE(0);
        __syncthreads();                   // buf1 staged; buf0 reads done
        if (t + 2 < 32) STAGE(0, (t + 2) * 32);
        COMPUTE(1);
        __syncthreads();                   // buf0 staged; buf1 reads done
    }

    if (which == 2) {
        // normal layout: acc[fi][fj][r] = C[m=fi*16+hi*4+r][c=fj*16+lo]
#pragma unroll
        for (int fj = 0; fj < 4; ++fj) {
            int c = bn * 128 + wn + fj * 16 + lo;
            int rem2 = c & 1023;
            int h = rem2 >> 6, d = rem2 & 63;
#pragma unroll
            for (int fi = 0; fi < 4; ++fi) {
                int m0 = bm * 128 + wm + fi * 16 + hi * 4;
                int b_ = m0 >> 11, n0 = m0 & 2047;
                u16x4 v;
#pragma unroll
                for (int r = 0; r < 4; ++r) v[r] = f2b(acc[fi][fj][r]);
                *(u16x4*)&Vt[((size_t)(b_ * 16 + h) * 64 + d) * 2048 + n0] = v;
            }
        }
    } else {
        // swapped layout: acc[fi][fj][r] = C[m=fi*16+lo][c=fj*16+hi*4+r]
        u16* T = (which == 0) ? Q : K;
        const float sc = (which == 0) ? 0.18033688011112042f : 1.0f;  // 0.125*log2e
#pragma unroll
        for (int fi = 0; fi < 4; ++fi) {
            int m = bm * 128 + wm + fi * 16 + lo;
            int b_ = m >> 11, n = m & 2047;
#pragma unroll
            for (int fj = 0; fj < 4; ++fj) {
                int c0 = bn * 128 + wn + fj * 16 + hi * 4;
                int rem2 = c0 & 1023;
                int h = rem2 >> 6, d0 = rem2 & 63;
                u16x4 v;
#pragma unroll
                for (int r = 0; r < 4; ++r) v[r] = f2b(acc[fi][fj][r] * sc);
                *(u16x4*)&T[((size_t)(b_ * 16 + h) * 2048 + n) * 64 + d0] = v;
            }
        }
    }
}

__global__ __launch_bounds__(256) void gemm_proj_mfma(
    const u16* __restrict__ A,    // AOb [8192][1024]
    const u16* __restrict__ Bt,   // wpT [1024][1024]
    const float* __restrict__ bias,
    float* __restrict__ Out)
{
    __shared__ u16 As[2][128 * 32];
    __shared__ u16 Bs[2][128 * 32];
    const int tid = threadIdx.x;
    const int w = tid >> 6, lane = tid & 63;
    // XCD swizzle: 512 blocks = 8 x (8bm x 8bn)
    const int flat = blockIdx.y * 8 + blockIdx.x;
    const int swz = (flat & 7) * 64 + (flat >> 3);
    const int bm = swz >> 3, bn = swz & 7;
    const int wm = (w >> 1) * 64, wn = (w & 1) * 64;
    const int lo = lane & 15, hi = lane >> 4;
    const int arow0 = w * 16 + (lane >> 2);
    const int akc = (lane & 3) * 8;

    f32x4 acc[4][4] = {};

    auto STAGE = [&](int bsel, int kt) {
#pragma unroll
        for (int j = 0; j < 2; ++j) {
            int row = j * 64 + arow0;
            gload16(&A[(size_t)(bm * 128 + row) * 1024 + kt + akc], &As[bsel][(j * 4 + w) * 512]);
            gload16(&Bt[(size_t)(bn * 128 + row) * 1024 + kt + akc], &Bs[bsel][(j * 4 + w) * 512]);
        }
    };

    auto COMPUTE = [&](int bsel) {
        bf16x8 a[4], b[4];
#pragma unroll
        for (int f = 0; f < 4; ++f) {
            a[f] = *(const bf16x8*)&As[bsel][(wm + f * 16 + lo) * 32 + hi * 8];
            b[f] = *(const bf16x8*)&Bs[bsel][(wn + f * 16 + lo) * 32 + hi * 8];
        }
#pragma unroll
        for (int fi = 0; fi < 4; ++fi)
#pragma unroll
            for (int fj = 0; fj < 4; ++fj)
                acc[fi][fj] = MFMA16(b[fj], a[fi], acc[fi][fj]);       // C^T: [c][m]
    };

    STAGE(0, 0);
    __syncthreads();
    for (int t = 0; t < 32; t += 2) {
        STAGE(1, (t + 1) * 32);
        COMPUTE(0);
        __syncthreads();
        if (t + 2 < 32) STAGE(0, (t + 2) * 32);
        COMPUTE(1);
        __syncthreads();
    }

    // swapped layout: acc[fi][fj][r] = C[m=fi*16+lo][c=fj*16+hi*4+r] -> float4
#pragma unroll
    for (int fi = 0; fi < 4; ++fi) {
        int m = bm * 128 + wm + fi * 16 + lo;
#pragma unroll
        for (int fj = 0; fj < 4; ++fj) {
            int c0 = bn * 128 + wn + fj * 16 + hi * 4;
            float4 bb = *(const float4*)&bias[c0];
            float4 o;
            o.x = acc[fi][fj][0] + bb.x;
            o.y = acc[fi][fj][1] + bb.y;
            o.z = acc[fi][fj][2] + bb.z;
            o.w = acc[fi][fj][3] + bb.w;
            *(float4*)&Out[(size_t)m * 1024 + c0] = o;
        }
    }
}

// ---------------------------------------------------------------------------
// Flash attention, bf16 MFMA, swapped QK^T, static-max softmax, blocked LDS,
// T14 async reg-staging: K/V tile t+1 loaded into 16 VGPRs BEFORE compute(t);
// ds_write after the next barrier (vmcnt wait lands on loads ~1 tile old).
// LDS stays 32 KB -> 4 blocks/CU. XCD-swizzled grid (unchanged).
// ---------------------------------------------------------------------------
__global__ __launch_bounds__(256, 4) void attn_mfma(
    const u16* __restrict__ Q, const u16* __restrict__ K,
    const u16* __restrict__ Vt, u16* __restrict__ AO)
{
    __shared__ u16 Ks[8 * 64 * 8];          // 8 KB
    __shared__ u16 Vs[8 * 64 * 8];          // 8 KB
    __shared__ u16 Ps[4][2][8 * 16 * 8];    // 16 KB
    const int tid = threadIdx.x;
    const int w = tid >> 6, lane = tid & 63;
    const int lo = lane & 15, hi = lane >> 4;

    const int flat = blockIdx.y * 16 + blockIdx.x;
    const int remap = (flat & 7) * 128 + (flat >> 3);
    const int bh = remap >> 4, qt = remap & 15;
    const int q0 = qt * 128 + w * 32;

    bf16x8 qf[2][2];
#pragma unroll
    for (int s = 0; s < 2; ++s)
#pragma unroll
        for (int fd = 0; fd < 2; ++fd)
            qf[s][fd] = *(const bf16x8*)&Q[((size_t)bh * 2048 + q0 + s * 16 + lo) * 64 + fd * 32 + hi * 8];

    const bf16x8 ones = { (short)0x3F80, (short)0x3F80, (short)0x3F80, (short)0x3F80,
                          (short)0x3F80, (short)0x3F80, (short)0x3F80, (short)0x3F80 };

    f32x4 o[2][4] = {};
    f32x4 ol[2] = {};

    const int rdKV = hi * 1024 + lo * 16;
    const int rdP  = hi * 256 + lo * 16;
    const int wrP  = lo * 16 + (hi >> 1) * 256 + (hi & 1) * 8;

    // per-thread staging state: cell (blk = w*2+ii, row = lane)
    uint4 kreg0, kreg1, vreg0, vreg1;
    const int blkA = w * 2, blkB = w * 2 + 1;

    auto LOADREGS = [&](int kt) {
        kreg0 = *(const uint4*)&K[((size_t)bh * 2048 + kt + lane) * 64 + blkA * 8];
        vreg0 = *(const uint4*)&Vt[((size_t)(bh * 64) + lane) * 2048 + kt + blkA * 8];
        kreg1 = *(const uint4*)&K[((size_t)bh * 2048 + kt + lane) * 64 + blkB * 8];
        vreg1 = *(const uint4*)&Vt[((size_t)(bh * 64) + lane) * 2048 + kt + blkB * 8];
    };

    auto DSWRITE = [&]() {
        *(uint4*)((char*)Ks + blkA * 1024 + lane * 16) = kreg0;
        *(uint4*)((char*)Vs + blkA * 1024 + lane * 16) = vreg0;
        *(uint4*)((char*)Ks + blkB * 1024 + lane * 16) = kreg1;
        *(uint4*)((char*)Vs + blkB * 1024 + lane * 16) = vreg1;
    };

    LOADREGS(0);

    for (int kt = 0; kt < 2048; kt += 64) {
        __syncthreads();            // prior tile's LDS reads done
        DSWRITE();                  // waits vmcnt on regs loaded 1 tile ago
        if (kt + 64 < 2048) LOADREGS(kt + 64);   // async: in flight over compute
        __syncthreads();            // writes visible

        f32x4 sacc[2][4] = {};
        __builtin_amdgcn_s_setprio(1);
#pragma unroll
        for (int fd = 0; fd < 2; ++fd) {
#pragma unroll
            for (int fn = 0; fn < 4; ++fn) {
                bf16x8 kf = *(const bf16x8*)((const char*)Ks + rdKV + fd * 4096 + fn * 256);
                sacc[0][fn] = MFMA16(kf, qf[0][fd], sacc[0][fn]);
                sacc[1][fn] = MFMA16(kf, qf[1][fd], sacc[1][fn]);
            }
        }
        __builtin_amdgcn_s_setprio(0);

#pragma unroll
        for (int s = 0; s < 2; ++s) {
            char* pw = (char*)&Ps[w][s][0] + wrP;
#pragma unroll
            for (int fn = 0; fn < 4; ++fn) {
                float p0 = exp2_(sacc[s][fn][0]);
                float p1 = exp2_(sacc[s][fn][1]);
                float p2 = exp2_(sacc[s][fn][2]);
                float p3 = exp2_(sacc[s][fn][3]);
                uint2 v;
                v.x = cvt_pk(p0, p1);
                v.y = cvt_pk(p2, p3);
                *(uint2*)(pw + fn * 512) = v;
            }
        }

        __builtin_amdgcn_s_setprio(1);
#pragma unroll
        for (int fk = 0; fk < 2; ++fk) {
            bf16x8 pa0 = *(const bf16x8*)((char*)&Ps[w][0][0] + rdP + fk * 1024);
            bf16x8 pa1 = *(const bf16x8*)((char*)&Ps[w][1][0] + rdP + fk * 1024);
            ol[0] = MFMA16(pa0, ones, ol[0]);
            ol[1] = MFMA16(pa1, ones, ol[1]);
#pragma unroll
            for (int fd = 0; fd < 4; ++fd) {
                bf16x8 vf = *(const bf16x8*)((const char*)Vs + rdKV + fk * 4096 + fd * 256);
                o[0][fd] = MFMA16(pa0, vf, o[0][fd]);
                o[1][fd] = MFMA16(pa1, vf, o[1][fd]);
            }
        }
        __builtin_amdgcn_s_setprio(0);
    }

    const int b_ = bh >> 4, h = bh & 15;
#pragma unroll
    for (int s = 0; s < 2; ++s) {
#pragma unroll
        for (int j = 0; j < 4; ++j) {
            float inv = 1.f / ol[s][j];
            int n = q0 + s * 16 + hi * 4 + j;
#pragma unroll
            for (int fd = 0; fd < 4; ++fd)
                AO[((size_t)b_ * 2048 + n) * 1024 + h * 64 + fd * 16 + lo] =
                    f2b(o[s][fd][j] * inv);
        }
    }
}

// ---------------------------------------------------------------------------
extern "C" void kernel_launch(void* const* d_in, const int* in_sizes, int n_in,
                              void* d_out, int out_size, void* d_ws, size_t ws_size,
                              hipStream_t stream) {
    (void)in_sizes; (void)n_in; (void)out_size; (void)ws_size;
    const float* x      = (const float*)d_in[0];
    const float* w_qkv  = (const float*)d_in[1];
    const float* w_proj = (const float*)d_in[2];
    const float* b_proj = (const float*)d_in[3];
    float* out = (float*)d_out;

    u16* ws  = (u16*)d_ws;
    u16* xb  = ws;                         // 8388608
    u16* wqT = xb + 8388608;               // 3145728
    u16* wpT = wqT + 3145728;              // 1048576
    u16* Qb  = wpT + 1048576;              // 8388608
    u16* Kb  = Qb + 8388608;               // 8388608
    u16* Vt  = Kb + 8388608;               // 8388608
    u16* AOb = Vt + 8388608;               // 8388608   total ~92 MB

    convert_x_kernel<<<4096, 256, 0, stream>>>(x, xb);
    transpose_conv_kernel<<<dim3(96, 32), dim3(32, 8), 0, stream>>>(w_qkv, wqT, 1024, 3072);
    transpose_conv_kernel<<<dim3(32, 32), dim3(32, 8), 0, stream>>>(w_proj, wpT, 1024, 1024);
    gemm_qkv_mfma<<<dim3(24, 64), 256, 0, stream>>>(xb, wqT, Qb, Kb, Vt);
    attn_mfma<<<dim3(16, 64), 256, 0, stream>>>(Qb, Kb, Vt, AOb);
    gemm_proj_mfma<<<dim3(8, 64), 256, 0, stream>>>(AOb, wpT, b_proj, out);
}

// Round 17
// 193.931 us; speedup vs baseline: 1.0422x; 1.0422x over previous
//
#include <hip/hip_runtime.h>
#include <hip/hip_bf16.h>

// B=4, N=2048, D=1024, H=16, hd=64. Full bf16-MFMA pipeline:
//  convert x / transpose-convert weights -> bf16
//  qkv GEMM (r8 128x128 2-phase dbuf + L2-GROUPED XCD grid)   [r15, best]
//  flash attention MFMA (swapped QK^T, static-max softmax, blocked-LDS,
//                        QBLK=256: 8 waves/block, half the stagings/CU)
//  proj GEMM (r8 128x128 2-phase dbuf, swapped-operand float4 epilogue)

typedef short bf16x8 __attribute__((ext_vector_type(8)));
typedef float f32x4 __attribute__((ext_vector_type(4)));
typedef unsigned short u16;
typedef u16 u16x8 __attribute__((ext_vector_type(8)));
typedef u16 u16x4 __attribute__((ext_vector_type(4)));

__device__ __forceinline__ u16 f2b(float f) {
    unsigned u = __builtin_bit_cast(unsigned, f);
    unsigned r = (u + 0x7fffu + ((u >> 16) & 1u)) >> 16;
    return (u16)r;
}

// v_cvt_pk_bf16_f32: a -> low16 (RNE), b -> high16
__device__ __forceinline__ unsigned cvt_pk(float a, float b) {
    unsigned r;
    asm("v_cvt_pk_bf16_f32 %0, %1, %2" : "=v"(r) : "v"(a), "v"(b));
    return r;
}

__device__ __forceinline__ float exp2_(float x) {
#if __has_builtin(__builtin_amdgcn_exp2f)
    return __builtin_amdgcn_exp2f(x);
#else
    return __expf(x * 0.69314718055994531f);
#endif
}

__device__ __forceinline__ void gload16(const void* g, void* lds) {
    __builtin_amdgcn_global_load_lds(
        (const __attribute__((address_space(1))) unsigned int*)g,
        (__attribute__((address_space(3))) unsigned int*)lds, 16, 0, 0);
}

#define MFMA16(a, b, c) __builtin_amdgcn_mfma_f32_16x16x32_bf16(a, b, c, 0, 0, 0)

// ---------------------------------------------------------------------------
__global__ __launch_bounds__(256) void convert_x_kernel(
    const float* __restrict__ in, u16* __restrict__ out)
{
    int i = blockIdx.x * 256 + threadIdx.x;
    const float4* ip = (const float4*)in;
    float4 a = ip[2 * i], b = ip[2 * i + 1];
    u16x8 r;
    r[0] = f2b(a.x); r[1] = f2b(a.y); r[2] = f2b(a.z); r[3] = f2b(a.w);
    r[4] = f2b(b.x); r[5] = f2b(b.y); r[6] = f2b(b.z); r[7] = f2b(b.w);
    *(u16x8*)&out[(size_t)i * 8] = r;
}

// in [R][C] fp32 -> out [C][R] bf16
__global__ __launch_bounds__(256) void transpose_conv_kernel(
    const float* __restrict__ in, u16* __restrict__ out, int R, int C)
{
    __shared__ float T[32][33];
    const int bj = blockIdx.x, bi = blockIdx.y;
    const int tx = threadIdx.x, ty = threadIdx.y;     // 32 x 8
#pragma unroll
    for (int k = 0; k < 4; ++k)
        T[ty + k * 8][tx] = in[(size_t)(bi * 32 + ty + k * 8) * C + bj * 32 + tx];
    __syncthreads();
#pragma unroll
    for (int k = 0; k < 4; ++k)
        out[(size_t)(bj * 32 + ty + k * 8) * R + bi * 32 + tx] = f2b(T[tx][ty + k * 8]);
}

// ---------------------------------------------------------------------------
// 128x128 tile bf16 GEMM, BK=32, 4 waves, 4x4 16x16 frags/wave (r8 structure).
// 2-phase dbuf + L2-grouped XCD grid (r15, best measured).
// ---------------------------------------------------------------------------
__global__ __launch_bounds__(256) void gemm_qkv_mfma(
    const u16* __restrict__ A,    // xb [8192][1024]
    const u16* __restrict__ Bt,   // wqT [3072][1024]
    u16* __restrict__ Q, u16* __restrict__ K, u16* __restrict__ Vt)
{
    __shared__ u16 As[2][128 * 32];
    __shared__ u16 Bs[2][128 * 32];
    const int tid = threadIdx.x;
    const int w = tid >> 6, lane = tid & 63;
    // L2-grouped XCD swizzle: 1536 = 8 XCD x 3 groups x (8bm x 8bn)
    const int flat = blockIdx.y * 24 + blockIdx.x;
    const int xcd = flat & 7, idx = flat >> 3;        // idx 0..191
    const int g = idx >> 6, rem = idx & 63;           // g 0..2
    const int bm = xcd * 8 + (rem >> 3);              // 0..63
    const int bn = g * 8 + (rem & 7);                 // 0..23
    const int wm = (w >> 1) * 64, wn = (w & 1) * 64;
    const int lo = lane & 15, hi = lane >> 4;
    const int arow0 = w * 16 + (lane >> 2);
    const int akc = (lane & 3) * 8;
    const int which = g;                  // 0=Q 1=K 2=V (block-uniform)

    f32x4 acc[4][4] = {};

    auto STAGE = [&](int bsel, int kt) {
#pragma unroll
        for (int j = 0; j < 2; ++j) {
            int row = j * 64 + arow0;
            gload16(&A[(size_t)(bm * 128 + row) * 1024 + kt + akc], &As[bsel][(j * 4 + w) * 512]);
            gload16(&Bt[(size_t)(bn * 128 + row) * 1024 + kt + akc], &Bs[bsel][(j * 4 + w) * 512]);
        }
    };

    auto COMPUTE = [&](int bsel) {
        bf16x8 a[4], b[4];
#pragma unroll
        for (int f = 0; f < 4; ++f) {
            a[f] = *(const bf16x8*)&As[bsel][(wm + f * 16 + lo) * 32 + hi * 8];
            b[f] = *(const bf16x8*)&Bs[bsel][(wn + f * 16 + lo) * 32 + hi * 8];
        }
        if (which == 2) {
#pragma unroll
            for (int fi = 0; fi < 4; ++fi)
#pragma unroll
                for (int fj = 0; fj < 4; ++fj)
                    acc[fi][fj] = MFMA16(a[fi], b[fj], acc[fi][fj]);   // C[m][c]
        } else {
#pragma unroll
            for (int fi = 0; fi < 4; ++fi)
#pragma unroll
                for (int fj = 0; fj < 4; ++fj)
                    acc[fi][fj] = MFMA16(b[fj], a[fi], acc[fi][fj]);   // C^T: [c][m]
        }
    };

    STAGE(0, 0);
    __syncthreads();                       // buf0 staged (implicit vmcnt(0))
    for (int t = 0; t < 32; t += 2) {
        STAGE(1, (t + 1) * 32);            // prefetch overlaps compute
        COMPUTE(0);
        __syncthreads();                   // buf1 staged; buf0 reads done
        if (t + 2 < 32) STAGE(0, (t + 2) * 32);
        COMPUTE(1);
        __syncthreads();                   // buf0 staged; buf1 reads done
    }

    if (which == 2) {
        // normal layout: acc[fi][fj][r] = C[m=fi*16+hi*4+r][c=fj*16+lo]
#pragma unroll
        for (int fj = 0; fj < 4; ++fj) {
            int c = bn * 128 + wn + fj * 16 + lo;
            int rem2 = c & 1023;
            int h = rem2 >> 6, d = rem2 & 63;
#pragma unroll
            for (int fi = 0; fi < 4; ++fi) {
                int m0 = bm * 128 + wm + fi * 16 + hi * 4;
                int b_ = m0 >> 11, n0 = m0 & 2047;
                u16x4 v;
#pragma unroll
                for (int r = 0; r < 4; ++r) v[r] = f2b(acc[fi][fj][r]);
                *(u16x4*)&Vt[((size_t)(b_ * 16 + h) * 64 + d) * 2048 + n0] = v;
            }
        }
    } else {
        // swapped layout: acc[fi][fj][r] = C[m=fi*16+lo][c=fj*16+hi*4+r]
        u16* T = (which == 0) ? Q : K;
        const float sc = (which == 0) ? 0.18033688011112042f : 1.0f;  // 0.125*log2e
#pragma unroll
        for (int fi = 0; fi < 4; ++fi) {
            int m = bm * 128 + wm + fi * 16 + lo;
            int b_ = m >> 11, n = m & 2047;
#pragma unroll
            for (int fj = 0; fj < 4; ++fj) {
                int c0 = bn * 128 + wn + fj * 16 + hi * 4;
                int rem2 = c0 & 1023;
                int h = rem2 >> 6, d0 = rem2 & 63;
                u16x4 v;
#pragma unroll
                for (int r = 0; r < 4; ++r) v[r] = f2b(acc[fi][fj][r] * sc);
                *(u16x4*)&T[((size_t)(b_ * 16 + h) * 2048 + n) * 64 + d0] = v;
            }
        }
    }
}

__global__ __launch_bounds__(256) void gemm_proj_mfma(
    const u16* __restrict__ A,    // AOb [8192][1024]
    const u16* __restrict__ Bt,   // wpT [1024][1024]
    const float* __restrict__ bias,
    float* __restrict__ Out)
{
    __shared__ u16 As[2][128 * 32];
    __shared__ u16 Bs[2][128 * 32];
    const int tid = threadIdx.x;
    const int w = tid >> 6, lane = tid & 63;
    // XCD swizzle: 512 blocks = 8 x (8bm x 8bn)
    const int flat = blockIdx.y * 8 + blockIdx.x;
    const int swz = (flat & 7) * 64 + (flat >> 3);
    const int bm = swz >> 3, bn = swz & 7;
    const int wm = (w >> 1) * 64, wn = (w & 1) * 64;
    const int lo = lane & 15, hi = lane >> 4;
    const int arow0 = w * 16 + (lane >> 2);
    const int akc = (lane & 3) * 8;

    f32x4 acc[4][4] = {};

    auto STAGE = [&](int bsel, int kt) {
#pragma unroll
        for (int j = 0; j < 2; ++j) {
            int row = j * 64 + arow0;
            gload16(&A[(size_t)(bm * 128 + row) * 1024 + kt + akc], &As[bsel][(j * 4 + w) * 512]);
            gload16(&Bt[(size_t)(bn * 128 + row) * 1024 + kt + akc], &Bs[bsel][(j * 4 + w) * 512]);
        }
    };

    auto COMPUTE = [&](int bsel) {
        bf16x8 a[4], b[4];
#pragma unroll
        for (int f = 0; f < 4; ++f) {
            a[f] = *(const bf16x8*)&As[bsel][(wm + f * 16 + lo) * 32 + hi * 8];
            b[f] = *(const bf16x8*)&Bs[bsel][(wn + f * 16 + lo) * 32 + hi * 8];
        }
#pragma unroll
        for (int fi = 0; fi < 4; ++fi)
#pragma unroll
            for (int fj = 0; fj < 4; ++fj)
                acc[fi][fj] = MFMA16(b[fj], a[fi], acc[fi][fj]);       // C^T: [c][m]
    };

    STAGE(0, 0);
    __syncthreads();
    for (int t = 0; t < 32; t += 2) {
        STAGE(1, (t + 1) * 32);
        COMPUTE(0);
        __syncthreads();
        if (t + 2 < 32) STAGE(0, (t + 2) * 32);
        COMPUTE(1);
        __syncthreads();
    }

    // swapped layout: acc[fi][fj][r] = C[m=fi*16+lo][c=fj*16+hi*4+r] -> float4
#pragma unroll
    for (int fi = 0; fi < 4; ++fi) {
        int m = bm * 128 + wm + fi * 16 + lo;
#pragma unroll
        for (int fj = 0; fj < 4; ++fj) {
            int c0 = bn * 128 + wn + fj * 16 + hi * 4;
            float4 bb = *(const float4*)&bias[c0];
            float4 o;
            o.x = acc[fi][fj][0] + bb.x;
            o.y = acc[fi][fj][1] + bb.y;
            o.z = acc[fi][fj][2] + bb.z;
            o.w = acc[fi][fj][3] + bb.w;
            *(float4*)&Out[(size_t)m * 1024 + c0] = o;
        }
    }
}

// ---------------------------------------------------------------------------
// Flash attention, bf16 MFMA, swapped QK^T, static-max softmax, blocked LDS.
// QBLK=256: 8 waves x 32 q-rows. Grid (8, 64) = 512 blocks (2/CU, resident).
// Per-CU K/V stagings halve vs QBLK=128 (same 16 waves/CU). gload_lds staging
// (r15-proven): wave w stages cell-plane blk=w, wave-uniform dst.
// LDS 48KB -> 3 blocks/CU capacity. XCD map: XCD x owns bh in [x*8,(x+1)*8)
// (4MB K/V per L2).
// ---------------------------------------------------------------------------
__global__ __launch_bounds__(512, 2) void attn_mfma(
    const u16* __restrict__ Q, const u16* __restrict__ K,
    const u16* __restrict__ Vt, u16* __restrict__ AO)
{
    __shared__ u16 Ks[8 * 64 * 8];          // 8 KB
    __shared__ u16 Vs[8 * 64 * 8];          // 8 KB
    __shared__ u16 Ps[8][2][8 * 16 * 8];    // 32 KB
    const int tid = threadIdx.x;
    const int w = tid >> 6, lane = tid & 63;   // w 0..7
    const int lo = lane & 15, hi = lane >> 4;

    // 512 blocks = 8 XCD x (8 bh x 8 qt)
    const int flat = blockIdx.y * 8 + blockIdx.x;
    const int remap = (flat & 7) * 64 + (flat >> 3);   // 0..511
    const int bh = remap >> 3, qt = remap & 7;
    const int q0 = qt * 256 + w * 32;

    bf16x8 qf[2][2];
#pragma unroll
    for (int s = 0; s < 2; ++s)
#pragma unroll
        for (int fd = 0; fd < 2; ++fd)
            qf[s][fd] = *(const bf16x8*)&Q[((size_t)bh * 2048 + q0 + s * 16 + lo) * 64 + fd * 32 + hi * 8];

    const bf16x8 ones = { (short)0x3F80, (short)0x3F80, (short)0x3F80, (short)0x3F80,
                          (short)0x3F80, (short)0x3F80, (short)0x3F80, (short)0x3F80 };

    f32x4 o[2][4] = {};
    f32x4 ol[2] = {};

    const int rdKV = hi * 1024 + lo * 16;
    const int rdP  = hi * 256 + lo * 16;
    const int wrP  = lo * 16 + (hi >> 1) * 256 + (hi & 1) * 8;

    for (int kt = 0; kt < 2048; kt += 64) {
        __syncthreads();            // prior tile's LDS reads done
        // wave w stages cell-plane blk = w (wave-uniform dst)
        gload16(&K[((size_t)bh * 2048 + kt + lane) * 64 + w * 8],
                (char*)Ks + w * 1024);
        gload16(&Vt[((size_t)(bh * 64) + lane) * 2048 + kt + w * 8],
                (char*)Vs + w * 1024);
        __syncthreads();            // staged

        f32x4 sacc[2][4] = {};
        __builtin_amdgcn_s_setprio(1);
#pragma unroll
        for (int fd = 0; fd < 2; ++fd) {
#pragma unroll
            for (int fn = 0; fn < 4; ++fn) {
                bf16x8 kf = *(const bf16x8*)((const char*)Ks + rdKV + fd * 4096 + fn * 256);
                sacc[0][fn] = MFMA16(kf, qf[0][fd], sacc[0][fn]);
                sacc[1][fn] = MFMA16(kf, qf[1][fd], sacc[1][fn]);
            }
        }
        __builtin_amdgcn_s_setprio(0);

#pragma unroll
        for (int s = 0; s < 2; ++s) {
            char* pw = (char*)&Ps[w][s][0] + wrP;
#pragma unroll
            for (int fn = 0; fn < 4; ++fn) {
                float p0 = exp2_(sacc[s][fn][0]);
                float p1 = exp2_(sacc[s][fn][1]);
                float p2 = exp2_(sacc[s][fn][2]);
                float p3 = exp2_(sacc[s][fn][3]);
                uint2 v;
                v.x = cvt_pk(p0, p1);
                v.y = cvt_pk(p2, p3);
                *(uint2*)(pw + fn * 512) = v;
            }
        }

        __builtin_amdgcn_s_setprio(1);
#pragma unroll
        for (int fk = 0; fk < 2; ++fk) {
            bf16x8 pa0 = *(const bf16x8*)((char*)&Ps[w][0][0] + rdP + fk * 1024);
            bf16x8 pa1 = *(const bf16x8*)((char*)&Ps[w][1][0] + rdP + fk * 1024);
            ol[0] = MFMA16(pa0, ones, ol[0]);
            ol[1] = MFMA16(pa1, ones, ol[1]);
#pragma unroll
            for (int fd = 0; fd < 4; ++fd) {
                bf16x8 vf = *(const bf16x8*)((const char*)Vs + rdKV + fk * 4096 + fd * 256);
                o[0][fd] = MFMA16(pa0, vf, o[0][fd]);
                o[1][fd] = MFMA16(pa1, vf, o[1][fd]);
            }
        }
        __builtin_amdgcn_s_setprio(0);
    }

    const int b_ = bh >> 4, h = bh & 15;
#pragma unroll
    for (int s = 0; s < 2; ++s) {
#pragma unroll
        for (int j = 0; j < 4; ++j) {
            float inv = 1.f / ol[s][j];
            int n = q0 + s * 16 + hi * 4 + j;
#pragma unroll
            for (int fd = 0; fd < 4; ++fd)
                AO[((size_t)b_ * 2048 + n) * 1024 + h * 64 + fd * 16 + lo] =
                    f2b(o[s][fd][j] * inv);
        }
    }
}

// ---------------------------------------------------------------------------
extern "C" void kernel_launch(void* const* d_in, const int* in_sizes, int n_in,
                              void* d_out, int out_size, void* d_ws, size_t ws_size,
                              hipStream_t stream) {
    (void)in_sizes; (void)n_in; (void)out_size; (void)ws_size;
    const float* x      = (const float*)d_in[0];
    const float* w_qkv  = (const float*)d_in[1];
    const float* w_proj = (const float*)d_in[2];
    const float* b_proj = (const float*)d_in[3];
    float* out = (float*)d_out;

    u16* ws  = (u16*)d_ws;
    u16* xb  = ws;                         // 8388608
    u16* wqT = xb + 8388608;               // 3145728
    u16* wpT = wqT + 3145728;              // 1048576
    u16* Qb  = wpT + 1048576;              // 8388608
    u16* Kb  = Qb + 8388608;               // 8388608
    u16* Vt  = Kb + 8388608;               // 8388608
    u16* AOb = Vt + 8388608;               // 8388608   total ~92 MB

    convert_x_kernel<<<4096, 256, 0, stream>>>(x, xb);
    transpose_conv_kernel<<<dim3(96, 32), dim3(32, 8), 0, stream>>>(w_qkv, wqT, 1024, 3072);
    transpose_conv_kernel<<<dim3(32, 32), dim3(32, 8), 0, stream>>>(w_proj, wpT, 1024, 1024);
    gemm_qkv_mfma<<<dim3(24, 64), 256, 0, stream>>>(xb, wqT, Qb, Kb, Vt);
    attn_mfma<<<dim3(8, 64), 512, 0, stream>>>(Qb, Kb, Vt, AOb);
    gemm_proj_mfma<<<dim3(8, 64), 256, 0, stream>>>(AOb, wpT, b_proj, out);
}